// Round 10
// baseline (270.456 us; speedup 1.0000x reference)
//
#include <hip/hip_runtime.h>
#include <math.h>

#define L 1024
#define NB 8
#define D 768
#define NEGV (-9.0e15f)
#define SCALE 0.036084391824351615f  // 1/sqrt(768)

typedef unsigned short u16;
typedef __attribute__((ext_vector_type(8))) short short8;
typedef __attribute__((ext_vector_type(4))) float float4v;
#define MFMA_BF16 __builtin_amdgcn_mfma_f32_16x16x32_bf16

__device__ __forceinline__ float b2f(u16 u) {
    union { unsigned int i; float f; } v; v.i = ((unsigned int)u) << 16; return v.f;
}
__device__ __forceinline__ u16 f2b(float f) {
    union { float fv; unsigned int i; } v; v.fv = f;
    unsigned int x = v.i;
    x += 0x7fffu + ((x >> 16) & 1u);   // RNE
    return (u16)(x >> 16);
}
__device__ __forceinline__ float unpk(unsigned int w, int h) {
    return b2f((u16)(h ? (w >> 16) : (w & 0xffffu)));
}

template<int F32>
__device__ __forceinline__ float4 ld4(const void* p, size_t idx) {
    if (F32) return *(const float4*)((const float*)p + idx);
    ushort4 v = *(const ushort4*)((const u16*)p + idx);
    return make_float4(b2f(v.x), b2f(v.y), b2f(v.z), b2f(v.w));
}
template<int F32>
__device__ __forceinline__ float ld1(const void* p, size_t idx) {
    if (F32) return ((const float*)p)[idx];
    return b2f(((const u16*)p)[idx]);
}
__device__ __forceinline__ int ldid(const int* p, size_t idx, int is64) {
    return is64 ? p[idx * 2] : p[idx];
}

// inline dtype detection: sh[0]=1 if floats are f32, sh[1]=1 if ids are int64.
__device__ __forceinline__ void detect2(const void* x, const void* ids, int* sh) {
    int tid = threadIdx.x;
    if (tid < 64) {
        u16 u = ((const u16*)x)[tid * 2];
        int e = (u >> 7) & 0xFF;
        unsigned long long balf = __ballot(e >= 100 && e <= 140);
        int v = ((const int*)ids)[tid * 2 + 1];
        unsigned long long bali = __ballot(v != 0);
        if (tid == 0) {
            sh[0] = (__popcll(balf) < 32) ? 1 : 0;
            sh[1] = (bali == 0ULL) ? 1 : 0;
        }
    }
    __syncthreads();
}

// ---------------- workspace layout (bytes) ----------------
#define WS_FLAG  ((size_t)0)
#define WS_SEP   ((size_t)64)
#define WS_C0    ((size_t)128)
#define WS_Z0    ((size_t)192)
#define WS_W1    ((size_t)9472)
#define WS_GATE  ((size_t)18752)
#define WS_CSUP  ((size_t)51520)
#define WS_CREP  ((size_t)84288)
#define WS_AF    ((size_t)117056)
#define WS_WREP  ((size_t)141632)
#define WS_WSUP  ((size_t)166208)
#define WS_HACC  ((size_t)190784)
#define WS_ALOG  ((size_t)215360)
#define WS_T     ((size_t)248128)
#define WS_OACC  ((size_t)303104)
#define WS_XB    ((size_t)524288)
#define WS_Z     ((size_t)13107200)
#define WS_WB    ((size_t)31981568)   // 6*D*D bf16
#define WS_M     ((size_t)40370176)   // 3*D*D bf16

struct PP { const void* W[6]; const void* b[6]; };

// ---------------- bias bodies ----------------
template<int F32> __device__ void kbias_body(const void* W, const void* vec,
        float* out, float* vs, int xi) {
    int tid = threadIdx.x;
    for (int i = tid; i < D; i += 256) vs[i] = ld1<F32>(vec, i);
    __syncthreads();
    int row = xi * 64 + (tid >> 2);
    int sub = tid & 3;
    float acc = 0.f;
    for (int i = 0; i < 48; ++i) {
        int k = i * 16 + sub * 4;
        float4 wv = ld4<F32>(W, (size_t)row * D + k);
        acc += wv.x * vs[k] + wv.y * vs[k + 1] + wv.z * vs[k + 2] + wv.w * vs[k + 3];
    }
    acc += __shfl_xor(acc, 1);
    acc += __shfl_xor(acc, 2);
    if (sub == 0) out[row] = acc;
}
template<int F32> __device__ void kc0_body(const void* bq, const void* bk,
        float* c0, float* red) {
    int tid = threadIdx.x;
    float s = 0.f;
    for (int i = tid; i < D; i += 256) s += ld1<F32>(bq, i) * ld1<F32>(bk, i);
    red[tid] = s; __syncthreads();
    for (int st = 128; st > 0; st >>= 1) { if (tid < st) red[tid] += red[tid + st]; __syncthreads(); }
    if (tid == 0) c0[0] = red[0];
}

// ---------------- kx: fused x->bf16 + Wa row-dot + W->bf16 + bias rows ----------------
template<int F32> __device__ void kx_body(const void* x, const void* Wa,
        const void* ba, u16* xb, float* alog, float* ws2) {
    int tid = threadIdx.x;
    for (int i = tid; i < D; i += 256) ws2[i] = ld1<F32>(Wa, i);
    __syncthreads();
    int row = blockIdx.x * 32 + (tid >> 3);
    int sub = tid & 7;
    float a0 = 0.f;
    for (int i = 0; i < 24; ++i) {
        int k = i * 32 + sub * 4;
        float4 xv = ld4<F32>(x, (size_t)row * D + k);
        ushort4 o;
        o.x = f2b(xv.x); o.y = f2b(xv.y); o.z = f2b(xv.z); o.w = f2b(xv.w);
        *(ushort4*)(xb + (size_t)row * D + k) = o;
        a0 += xv.x * ws2[k] + xv.y * ws2[k + 1] + xv.z * ws2[k + 2] + xv.w * ws2[k + 3];
    }
    #pragma unroll
    for (int d = 1; d < 8; d <<= 1) a0 += __shfl_xor(a0, d);
    if (sub == 0) alog[row] = a0 + ld1<F32>(ba, 0);
}
__global__ __launch_bounds__(256) void kx(const void* x, const int* ids, PP pp,
        const void* Wa, const void* ba, u16* xb, u16* Wb, float* alog,
        float* z0, float* w1, float* c0f) {
    __shared__ float sf[2 * D];
    __shared__ int fsh[2];
    detect2(x, ids, fsh);
    int F32 = fsh[0];
    int bid = blockIdx.x;
    if (bid < 256) {
        if (F32) kx_body<1>(x, Wa, ba, xb, alog, sf);
        else     kx_body<0>(x, Wa, ba, xb, alog, sf);
        return;
    }
    if (bid < 1984) {
        int t = (bid - 256) / 288, inner = (bid - 256) % 288;
        const void* src = pp.W[t];
        u16* dst = Wb + (size_t)t * D * D;
        size_t base = ((size_t)inner * 256 + threadIdx.x) * 8;
        if (F32) {
            float4 a = *(const float4*)((const float*)src + base);
            float4 b = *(const float4*)((const float*)src + base + 4);
            uint4 o; u16* po = (u16*)&o;
            po[0] = f2b(a.x); po[1] = f2b(a.y); po[2] = f2b(a.z); po[3] = f2b(a.w);
            po[4] = f2b(b.x); po[5] = f2b(b.y); po[6] = f2b(b.z); po[7] = f2b(b.w);
            *(uint4*)(dst + base) = o;
        } else {
            *(uint4*)(dst + base) = *(const uint4*)((const u16*)src + base);
        }
        return;
    }
    int i = bid - 1984;            // 0..59
    int y = i / 12, xi = i % 12;
    float* vs = sf;
    float* red = sf + D;
    if (y == 4) {
        if (xi != 0) return;
        if (F32) kc0_body<1>(pp.b[2], pp.b[3], c0f, red);
        else     kc0_body<0>(pp.b[2], pp.b[3], c0f, red);
        return;
    }
    const void* W; const void* vec; float* out;
    if (y < 3) { W = pp.W[2 * y + 1]; vec = pp.b[2 * y]; out = z0 + y * D; }
    else       { W = pp.W[2];         vec = pp.b[3];     out = w1; }
    if (F32) kbias_body<1>(W, vec, out, vs, xi);
    else     kbias_body<0>(W, vec, out, vs, xi);
}

// ================= staging with involutory col-block swizzle =================
__device__ __forceinline__ void stage128_async(const u16* __restrict__ G, size_t ld,
        int r0, int k0, u16* S, int tid) {
    int rowa = tid >> 2;
    int koa = ((tid & 3) ^ (rowa & 3)) << 3;
    int wave = tid >> 6;
    const u16* g1 = &G[(size_t)(r0 + rowa) * ld + k0 + koa];
    const u16* g2 = &G[(size_t)(r0 + rowa + 64) * ld + k0 + koa];
    __builtin_amdgcn_global_load_lds((__attribute__((address_space(1))) void*)(u16*)g1,
        (__attribute__((address_space(3))) void*)(S + wave * 512), 16, 0, 0);
    __builtin_amdgcn_global_load_lds((__attribute__((address_space(1))) void*)(u16*)g2,
        (__attribute__((address_space(3))) void*)(S + 2048 + wave * 512), 16, 0, 0);
}
__device__ __forceinline__ void stage64_async(const u16* __restrict__ G, size_t ld,
        int r0, int k0, u16* S, int tid) {
    int rowa = tid >> 2;
    int koa = ((tid & 3) ^ (rowa & 3)) << 3;
    int wave = tid >> 6;
    const u16* g = &G[(size_t)(r0 + rowa) * ld + k0 + koa];
    __builtin_amdgcn_global_load_lds((__attribute__((address_space(1))) void*)(u16*)g,
        (__attribute__((address_space(3))) void*)(S + wave * 512), 16, 0, 0);
}

// ============ counted-vmcnt 2-buffer GEMM cores ============
// BM=64, BN=128, K=768. As: 2x4096 u16 (16KB), Bs: 2x8192 u16 (32KB). 6 loads/iter.
__device__ __forceinline__ void gemm64_cnt(const u16* __restrict__ A, size_t lda, int r0,
        const u16* __restrict__ B, size_t ldb, int c0,
        u16* As, u16* Bs, float4v acc[2][4]) {
    int tid = threadIdx.x;
    int lane = tid & 63, wave = tid >> 6;
    int wm = (wave >> 1) << 5, wn = (wave & 1) << 6;
    int quad = lane >> 4, lrow = lane & 15;
    int sq = ((quad ^ (lrow & 3)) << 3);
    #pragma unroll
    for (int i = 0; i < 2; ++i)
        #pragma unroll
        for (int j = 0; j < 4; ++j) acc[i][j] = (float4v){0.f, 0.f, 0.f, 0.f};
    stage64_async(A, lda, r0, 0, As, tid);
    stage64_async(A, lda, r0, 32, As + 2048, tid);
    stage128_async(B, ldb, c0, 0, Bs, tid);
    stage128_async(B, ldb, c0, 32, Bs + 4096, tid);
    stage64_async(A, lda, r0, 64, As + 4096, tid);
    stage64_async(A, lda, r0, 96, As + 6144, tid);
    stage128_async(B, ldb, c0, 64, Bs + 8192, tid);
    stage128_async(B, ldb, c0, 96, Bs + 12288, tid);
    #pragma unroll 1
    for (int t = 0; t < 12; ++t) {
        int cur = t & 1;
        if (t != 11) asm volatile("s_waitcnt vmcnt(6)" ::: "memory");
        else         asm volatile("s_waitcnt vmcnt(0)" ::: "memory");
        __builtin_amdgcn_s_barrier();
        const u16* Ab = As + cur * 4096;
        const u16* Bb = Bs + cur * 8192;
        short8 fa[2][2], fb[2][4];
        #pragma unroll
        for (int p = 0; p < 2; ++p) {
            #pragma unroll
            for (int i = 0; i < 2; ++i)
                fa[p][i] = *(const short8*)&Ab[p * 2048 + (wm + i * 16 + lrow) * 32 + sq];
            #pragma unroll
            for (int j = 0; j < 4; ++j)
                fb[p][j] = *(const short8*)&Bb[p * 4096 + (wn + j * 16 + lrow) * 32 + sq];
        }
        asm volatile("s_waitcnt lgkmcnt(0)" ::: "memory");
        __builtin_amdgcn_sched_barrier(0);
        __builtin_amdgcn_s_barrier();
        if (t < 10) {
            int k0 = (t + 2) << 6;
            u16* Ad = As + cur * 4096;
            u16* Bd = Bs + cur * 8192;
            stage64_async(A, lda, r0, k0, Ad, tid);
            stage64_async(A, lda, r0, k0 + 32, Ad + 2048, tid);
            stage128_async(B, ldb, c0, k0, Bd, tid);
            stage128_async(B, ldb, c0, k0 + 32, Bd + 4096, tid);
        }
        #pragma unroll
        for (int p = 0; p < 2; ++p)
            #pragma unroll
            for (int i = 0; i < 2; ++i)
                #pragma unroll
                for (int j = 0; j < 4; ++j)
                    acc[i][j] = MFMA_BF16(fa[p][i], fb[p][j], acc[i][j], 0, 0, 0);
    }
}

// BM=128, BN=128. As: 2x8192 u16 (32KB), Bs: 2x8192 u16 (32KB). 8 loads/iter.
__device__ __forceinline__ void gemm128_cnt(const u16* __restrict__ A, size_t lda, int r0,
        const u16* __restrict__ B, size_t ldb, int c0,
        u16* As, u16* Bs, float4v acc[4][4]) {
    int tid = threadIdx.x;
    int lane = tid & 63, wave = tid >> 6;
    int wm = (wave >> 1) << 6, wn = (wave & 1) << 6;
    int quad = lane >> 4, lrow = lane & 15;
    int sq = ((quad ^ (lrow & 3)) << 3);
    #pragma unroll
    for (int i = 0; i < 4; ++i)
        #pragma unroll
        for (int j = 0; j < 4; ++j) acc[i][j] = (float4v){0.f, 0.f, 0.f, 0.f};
    stage128_async(A, lda, r0, 0, As, tid);
    stage128_async(A, lda, r0, 32, As + 4096, tid);
    stage128_async(B, ldb, c0, 0, Bs, tid);
    stage128_async(B, ldb, c0, 32, Bs + 4096, tid);
    stage128_async(A, lda, r0, 64, As + 8192, tid);
    stage128_async(A, lda, r0, 96, As + 12288, tid);
    stage128_async(B, ldb, c0, 64, Bs + 8192, tid);
    stage128_async(B, ldb, c0, 96, Bs + 12288, tid);
    #pragma unroll 1
    for (int t = 0; t < 12; ++t) {
        int cur = t & 1;
        if (t != 11) asm volatile("s_waitcnt vmcnt(8)" ::: "memory");
        else         asm volatile("s_waitcnt vmcnt(0)" ::: "memory");
        __builtin_amdgcn_s_barrier();
        const u16* Ab = As + cur * 8192;
        const u16* Bb = Bs + cur * 8192;
        short8 fa[2][4], fb[2][4];
        #pragma unroll
        for (int p = 0; p < 2; ++p) {
            #pragma unroll
            for (int i = 0; i < 4; ++i)
                fa[p][i] = *(const short8*)&Ab[p * 4096 + (wm + i * 16 + lrow) * 32 + sq];
            #pragma unroll
            for (int j = 0; j < 4; ++j)
                fb[p][j] = *(const short8*)&Bb[p * 4096 + (wn + j * 16 + lrow) * 32 + sq];
        }
        asm volatile("s_waitcnt lgkmcnt(0)" ::: "memory");
        __builtin_amdgcn_sched_barrier(0);
        __builtin_amdgcn_s_barrier();
        if (t < 10) {
            int k0 = (t + 2) << 6;
            u16* Ad = As + cur * 8192;
            u16* Bd = Bs + cur * 8192;
            stage128_async(A, lda, r0, k0, Ad, tid);
            stage128_async(A, lda, r0, k0 + 32, Ad + 4096, tid);
            stage128_async(B, ldb, c0, k0, Bd, tid);
            stage128_async(B, ldb, c0, k0 + 32, Bd + 4096, tid);
        }
        #pragma unroll
        for (int p = 0; p < 2; ++p)
            #pragma unroll
            for (int i = 0; i < 4; ++i)
                #pragma unroll
                for (int j = 0; j < 4; ++j)
                    acc[i][j] = MFMA_BF16(fa[p][i], fb[p][j], acc[i][j], 0, 0, 0);
    }
}

// ---------------- kB: blocks 0..7 gate/sep/zero; 8..223 kM; 224..255 tbuf ----------------
__global__ __launch_bounds__(256) void kB(const void* x, const int* __restrict__ ids,
        const int* __restrict__ padp, const float* __restrict__ alog,
        float* __restrict__ gate, int* __restrict__ sepArr,
        float* __restrict__ af, float* __restrict__ wrep, float* __restrict__ wsup,
        float* __restrict__ hacc, float* __restrict__ oacc,
        float* __restrict__ csup, float* __restrict__ crep,
        const u16* __restrict__ xb, const float* __restrict__ w1,
        const float* __restrict__ c0f, float* __restrict__ tbuf,
        const u16* __restrict__ Wb, u16* __restrict__ Mt) {
    __shared__ __align__(16) u16 SMEM[24576];   // 48 KB
    int bid = blockIdx.x;
    int tid = threadIdx.x;
    if (bid >= 8 && bid < 224) {
        int i = bid - 8;
        int p = i / 72, j = i % 72;
        int r0 = (j / 6) * 64, c0m = (j % 6) * 128;
        u16* As = SMEM;
        u16* Bs = SMEM + 8192;
        float4v acc[2][4];
        gemm64_cnt(Wb + (size_t)(2 * p + 1) * D * D, D, r0,
                   Wb + (size_t)(2 * p) * D * D, D, c0m, As, Bs, acc);
        int lane = tid & 63, wave = tid >> 6;
        int wm = (wave >> 1) << 5, wn = (wave & 1) << 6;
        int quad = lane >> 4, lrow = lane & 15;
        u16* out = Mt + (size_t)p * D * D;
        #pragma unroll
        for (int ii = 0; ii < 2; ++ii)
            #pragma unroll
            for (int jj = 0; jj < 4; ++jj) {
                int brow = r0 + wm + ii * 16 + quad * 4;
                int col = c0m + wn + jj * 16 + lrow;
                #pragma unroll
                for (int r = 0; r < 4; ++r)
                    out[(size_t)(brow + r) * D + col] = f2b(acc[ii][jj][r]);
            }
        return;
    }
    if (bid >= 224) {
        int i = bid - 224;
        int b = i >> 2, q = i & 3;
        float* w1s = (float*)SMEM;
        for (int j = tid; j < D; j += 256) w1s[j] = w1[j];
        __syncthreads();
        float c0v = c0f[0];
        int sub = tid & 15;
        int rowi = tid >> 4;
        for (int pass = 0; pass < 8; ++pass) {
            int l = q * 128 + pass * 16 + rowi;
            const u16* xr = xb + ((size_t)b * L + l) * D;
            float a = 0.f;
            #pragma unroll
            for (int i2 = 0; i2 < 6; ++i2) {
                int k = i2 * 128 + sub * 8;
                short8 v = *(const short8*)&xr[k];
                #pragma unroll
                for (int e = 0; e < 8; ++e) a += b2f((u16)v[e]) * w1s[k + e];
            }
            #pragma unroll
            for (int d2 = 1; d2 < 16; d2 <<= 1) a += __shfl_xor(a, d2);
            if (sub == 0) tbuf[b * 512 + l] = a + c0v;
        }
        return;
    }
    // --- gate/sep/zero (blocks 0..7) ---
    float* red = (float*)SMEM;
    int*   ish = (int*)(red + 256);
    detect2(x, ids, ish);
    int is64 = ish[1];
    int b = bid;
    int pad = padp[0];
    int cnt = 0;
    for (int l = tid; l < L; l += 256) cnt += (ldid(ids, (size_t)b * L + l, is64) != pad) ? 1 : 0;
    red[tid] = (float)cnt; __syncthreads();
    for (int s = 128; s > 0; s >>= 1) { if (tid < s) red[tid] += red[tid + s]; __syncthreads(); }
    if (tid == 0) {
        int vl = (int)red[0];
        int sep = vl / 2; if (sep < 1) sep = 1; if (sep > L - 2) sep = L - 2;
        ish[2] = sep; sepArr[b] = sep;
    }
    __syncthreads();
    int sep = ish[2];
    float lv[4]; int lidx[4];
    float mx = -3.4e38f;
    for (int u = 0; u < 4; ++u) {
        int l = tid + u * 256; lidx[u] = l;
        bool fm = (l < sep) && (ldid(ids, (size_t)b * L + l, is64) != pad);
        float v = fm ? alog[b * L + l] : NEGV;
        lv[u] = v; mx = fmaxf(mx, v);
    }
    red[tid] = mx; __syncthreads();
    for (int s = 128; s > 0; s >>= 1) { if (tid < s) red[tid] = fmaxf(red[tid], red[tid + s]); __syncthreads(); }
    mx = red[0]; __syncthreads();
    float se = 0.f;
    for (int u = 0; u < 4; ++u) { lv[u] = expf(lv[u] - mx); se += lv[u]; }
    red[tid] = se; __syncthreads();
    for (int s = 128; s > 0; s >>= 1) { if (tid < s) red[tid] += red[tid + s]; __syncthreads(); }
    float den = fmaxf(red[0], 1e-30f); __syncthreads();
    float gs = 0.f; float gv[4];
    for (int u = 0; u < 4; ++u) {
        int l = lidx[u];
        bool fm = (l < sep) && (ldid(ids, (size_t)b * L + l, is64) != pad);
        float p = lv[u] / den;
        gv[u] = fm ? p : 0.f;
        gs += gv[u];
    }
    red[tid] = gs; __syncthreads();
    for (int s = 128; s > 0; s >>= 1) { if (tid < s) red[tid] += red[tid + s]; __syncthreads(); }
    gs = red[0];
    float inv = 1.f / fmaxf(gs, 1e-8f);
    for (int u = 0; u < 4; ++u) gate[b * L + lidx[u]] = gv[u] * inv;
    for (int l = tid; l < L; l += 256) { csup[b * L + l] = 0.f; crep[b * L + l] = 0.f; }
    for (int i = tid; i < D; i += 256) {
        af[b * D + i] = 0.f; wrep[b * D + i] = 0.f; wsup[b * D + i] = 0.f;
        hacc[b * D + i] = 0.f; oacc[b * D + i] = 0.f;
    }
}

// ---------------- kZ: Z[l][j] = sum_k xb[l][k] Mt[j][k] + z0[j] ----------------
__global__ __launch_bounds__(256) void kZ_mfma(const u16* __restrict__ xb,
        const u16* __restrict__ Mt, const float* __restrict__ z0,
        u16* __restrict__ Zbuf, const int* __restrict__ sepArr) {
    __shared__ __align__(16) u16 As[16384];
    __shared__ __align__(16) u16 Bs[16384];
    int z = blockIdx.z;
    int p = z >> 3, b = z & 7;
    int sep = sepArr[b];
    int r0 = blockIdx.y * 128;
    if (r0 >= sep) return;
    int c0 = blockIdx.x * 128;
    float4v acc[4][4];
    gemm128_cnt(xb + (size_t)b * L * D, D, r0,
                Mt + (size_t)p * D * D, D, c0, As, Bs, acc);
    int lane = threadIdx.x & 63, wave = threadIdx.x >> 6;
    int wm = (wave >> 1) << 6, wn = (wave & 1) << 6;
    int quad = lane >> 4, lrow = lane & 15;
    const float* z0p = z0 + p * D;
    u16* out = Zbuf + ((size_t)p * NB + b) * 512 * D;
    #pragma unroll
    for (int i = 0; i < 4; ++i)
        #pragma unroll
        for (int j = 0; j < 4; ++j) {
            int brow = r0 + wm + i * 16 + quad * 4;
            int col = c0 + wn + j * 16 + lrow;
            float zb = z0p[col];
            #pragma unroll
            for (int r = 0; r < 4; ++r)
                out[(size_t)(brow + r) * D + col] = f2b(acc[i][j][r] + zb);
        }
}

// ---------------- kS2: 16-wave pair-split; con/rep A in LDS; A0/B register-direct ----------------
// 256 blocks x 1024 threads (16 waves = 4 waves/SIMD), b = bid&7, 16 Q-rows/block.
// Work unit = (chunk, col-group-of-16) pair; npairs = nchunk*8 (typically 32 since
// sep~512 -> nchunk=4). Wave w owns pairs {2w, 2w+1} (+32 per extra pass).
// Per wave: acc[3 mats][2 pairs]; 3 asm loads/step (supA + 2 B), 3-deep rotation,
// 9 in flight, vmcnt(6)+sched_barrier. con/rep A read from 49KB swizzled LDS.
__global__ __launch_bounds__(1024) void kS2(const u16* __restrict__ Zbuf,
        const u16* __restrict__ xb, const float* __restrict__ tcbuf,
        const int* __restrict__ sepArr, const int* __restrict__ ids,
        const int* __restrict__ padp, const float* __restrict__ gate,
        float* __restrict__ csup, float* __restrict__ crep) {
    __shared__ __align__(16) u16 Alds[24576];   // 2 mats * 16 rows * 96 slots * 8 u16 = 49152 B
    __shared__ float redmx[2][16][16];
    __shared__ float redsm[2][16][16];
    __shared__ int ish[1];
    int bid = blockIdx.x;
    int b = bid & 7;
    int l0 = (bid >> 3) * 16;
    int sep = sepArr[b];
    int tid = threadIdx.x, lane = tid & 63, wave = tid >> 6;   // wave 0..15
    int lrow = lane & 15, quad = lane >> 4;
    if (tid < 64) {
        int v = ((const int*)ids)[tid * 2 + 1];
        unsigned long long bali = __ballot(v != 0);
        if (tid == 0) ish[0] = (bali == 0ULL) ? 1 : 0;
    }
    __syncthreads();
    if (l0 >= sep) return;      // block-uniform
    int is64 = ish[0];
    int pad = padp[0];
    int msta = ((sep + 1) >> 7) << 7;
    int nchunk = (L - msta) >> 7;
    int npairs = nchunk * 8;
    const u16* A0 = Zbuf + (size_t)b * 512 * D;              // sup (register-direct)
    const u16* A1 = Zbuf + ((size_t)NB + b) * 512 * D;       // con -> LDS mat 0
    const u16* A2 = Zbuf + ((size_t)2 * NB + b) * 512 * D;   // rep -> LDS mat 1
    const u16* X  = xb + (size_t)b * L * D;
    // ---- stage con+rep once: slot s -> mat m, row r, col-slot c (16B each) ----
    #pragma unroll
    for (int i = 0; i < 3; ++i) {
        int s = tid + i * 1024;          // 0..3071
        int m = s / 1536, rem = s - m * 1536;
        int r = rem / 96, c = rem - r * 96;
        const u16* src = (m == 0 ? A1 : A2) + (size_t)(l0 + r) * D + c * 8;
        *(short8*)&Alds[(((m * 16 + r) * 96) + (c ^ (r & 7))) * 8] = *(const short8*)src;
    }
    __syncthreads();
    float tcv[4], gr[4];
    #pragma unroll
    for (int r = 0; r < 4; ++r) {
        tcv[r] = tcbuf[b * 512 + l0 + quad * 4 + r];
        gr[r]  = gate[b * L + l0 + quad * 4 + r];
    }
    int xr = lrow & 7;
    int arow0 = lrow * 768;              // u16 index of row base (96 slots * 8)
    const u16* pA0_ = A0 + (size_t)(l0 + lrow) * D + quad * 8;
    const unsigned NEGP = (unsigned)f2b(NEGV) | ((unsigned)f2b(NEGV) << 16);
    unsigned int pS[4][2], pC[4][2];
    #pragma unroll
    for (int pass = 0; pass < 2; ++pass) {
      if (pass * 32 < npairs) {
        int p0 = pass * 32 + wave * 2;
        int p1 = p0 + 1;
        int r0a = msta + (p0 >> 3) * 128 + (p0 & 7) * 16; if (r0a > L - 16) r0a = L - 16;
        int r1a = msta + (p1 >> 3) * 128 + (p1 & 7) * 16; if (r1a > L - 16) r1a = L - 16;
        const u16* pB0_ = X + (size_t)(r0a + lrow) * D + quad * 8;
        const u16* pB1_ = X + (size_t)(r1a + lrow) * D + quad * 8;
        float4v acc[3][2];
        #pragma unroll
        for (int m = 0; m < 3; ++m)
            #pragma unroll
            for (int s2 = 0; s2 < 2; ++s2) acc[m][s2] = (float4v){0.f, 0.f, 0.f, 0.f};
        short8 fA1, fA2;
        short8 A0a, B0a, B1a;
        short8 A0b, B0b, B1b;
        short8 A0c, B0c, B1c;
#define GL_(dst, base, imm) asm volatile("global_load_dwordx4 %0, %1, off offset:" #imm : "=v"(dst) : "v"(base))
#define GL(dst, base, imm) GL_(dst, base, imm)
#define LDG3(SUF, IMM) do { \
        GL(A0##SUF, pA0_, IMM); \
        GL(B0##SUF, pB0_, IMM); GL(B1##SUF, pB1_, IMM); } while (0)
#define LDA(S) do { int sw = (((4 * (S) + quad) ^ xr) << 3); \
        fA1 = *(const short8*)&Alds[arow0 + sw]; \
        fA2 = *(const short8*)&Alds[12288 + arow0 + sw]; } while (0)
#define WAITN_(N) do { asm volatile("s_waitcnt vmcnt(" #N ")"); \
        __builtin_amdgcn_sched_barrier(0); } while (0)
#define WAITN(N) WAITN_(N)
#define CPSTEP(SUF) do { \
        acc[0][0] = MFMA_BF16(A0##SUF, B0##SUF, acc[0][0], 0, 0, 0); \
        acc[1][0] = MFMA_BF16(fA1, B0##SUF, acc[1][0], 0, 0, 0); \
        acc[2][0] = MFMA_BF16(fA2, B0##SUF, acc[2][0], 0, 0, 0); \
        acc[0][1] = MFMA_BF16(A0##SUF, B1##SUF, acc[0][1], 0, 0, 0); \
        acc[1][1] = MFMA_BF16(fA1, B1##SUF, acc[1][1], 0, 0, 0); \
        acc[2][1] = MFMA_BF16(fA2, B1##SUF, acc[2][1], 0, 0, 0); } while (0)
        // drain unrelated VMEM so manual vmcnt counting is exact
        WAITN(0);
        LDG3(a, 0); LDG3(b, 64); LDG3(c, 128);
        LDA(0);  WAITN(6); CPSTEP(a); LDG3(a, 192);
        LDA(1);  WAITN(6); CPSTEP(b); LDG3(b, 256);
        LDA(2);  WAITN(6); CPSTEP(c); LDG3(c, 320);
        LDA(3);  WAITN(6); CPSTEP(a); LDG3(a, 384);
        LDA(4);  WAITN(6); CPSTEP(b); LDG3(b, 448);
        LDA(5);  WAITN(6); CPSTEP(c); LDG3(c, 512);
        LDA(6);  WAITN(6); CPSTEP(a); LDG3(a, 576);
        LDA(7);  WAITN(6); CPSTEP(b); LDG3(b, 640);
        LDA(8);  WAITN(6); CPSTEP(c); LDG3(c, 704);
        LDA(9);  WAITN(6); CPSTEP(a); LDG3(a, 768);
        LDA(10); WAITN(6); CPSTEP(b); LDG3(b, 832);
        LDA(11); WAITN(6); CPSTEP(c); LDG3(c, 896);
        LDA(12); WAITN(6); CPSTEP(a); LDG3(a, 960);
        LDA(13); WAITN(6); CPSTEP(b); LDG3(b, 1024);
        LDA(14); WAITN(6); CPSTEP(c); LDG3(c, 1088);
        LDA(15); WAITN(6); CPSTEP(a); LDG3(a, 1152);
        LDA(16); WAITN(6); CPSTEP(b); LDG3(b, 1216);
        LDA(17); WAITN(6); CPSTEP(c); LDG3(c, 1280);
        LDA(18); WAITN(6); CPSTEP(a); LDG3(a, 1344);
        LDA(19); WAITN(6); CPSTEP(b); LDG3(b, 1408);
        LDA(20); WAITN(6); CPSTEP(c); LDG3(c, 1472);
        LDA(21); WAITN(6); CPSTEP(a);
        LDA(22); WAITN(3); CPSTEP(b);
        LDA(23); WAITN(0); CPSTEP(c);
#undef GL_
#undef GL
#undef LDG3
#undef LDA
#undef WAITN_
#undef WAITN
#undef CPSTEP
        // fold to masked bf16 scores
        #pragma unroll
        for (int s2 = 0; s2 < 2; ++s2) {
            int pr = p0 + s2;
            int m = msta + (pr >> 3) * 128 + (pr & 7) * 16 + lrow;
            bool ok = (pr < npairs) && (m > sep) && (m < L)
                      && (ldid(ids, (size_t)b * L + m, is64) != pad);
            float vs[4], vc[4];
            #pragma unroll
            for (int r = 0; r < 4; ++r) {
                vs[r] = ok ? acc[0][s2][r] * SCALE : NEGV;
                vc[r] = ok ? (acc[2][s2][r] * SCALE
                              + tanhf((acc[1][s2][r] + tcv[r]) * SCALE)) : NEGV;
            }
            pS[pass * 2 + s2][0] = (unsigned)f2b(vs[0]) | ((unsigned)f2b(vs[1]) << 16);
            pS[pass * 2 + s2][1] = (unsigned)f2b(vs[2]) | ((unsigned)f2b(vs[3]) << 16);
            pC[pass * 2 + s2][0] = (unsigned)f2b(vc[0]) | ((unsigned)f2b(vc[1]) << 16);
            pC[pass * 2 + s2][1] = (unsigned)f2b(vc[2]) | ((unsigned)f2b(vc[3]) << 16);
        }
      } else {
        #pragma unroll
        for (int s2 = 0; s2 < 2; ++s2) {
            pS[pass * 2 + s2][0] = NEGP; pS[pass * 2 + s2][1] = NEGP;
            pC[pass * 2 + s2][0] = NEGP; pC[pass * 2 + s2][1] = NEGP;
        }
      }
    }
    // ---- row max (own slots, then lrow within wave, then across 16 waves) ----
    float mxs[4], mxc[4];
    #pragma unroll
    for (int r = 0; r < 4; ++r) { mxs[r] = -3.4e38f; mxc[r] = -3.4e38f; }
    #pragma unroll
    for (int ps = 0; ps < 4; ++ps)
        #pragma unroll
        for (int r = 0; r < 4; ++r) {
            mxs[r] = fmaxf(mxs[r], unpk(pS[ps][r >> 1], r & 1));
            mxc[r] = fmaxf(mxc[r], unpk(pC[ps][r >> 1], r & 1));
        }
    #pragma unroll
    for (int d = 1; d < 16; d <<= 1)
        #pragma unroll
        for (int r = 0; r < 4; ++r) {
            mxs[r] = fmaxf(mxs[r], __shfl_xor(mxs[r], d));
            mxc[r] = fmaxf(mxc[r], __shfl_xor(mxc[r], d));
        }
    if (lrow == 0)
        #pragma unroll
        for (int r = 0; r < 4; ++r) {
            redmx[0][wave][quad * 4 + r] = mxs[r];
            redmx[1][wave][quad * 4 + r] = mxc[r];
        }
    __syncthreads();
    #pragma unroll
    for (int r = 0; r < 4; ++r) {
        int rr = quad * 4 + r;
        float m0 = redmx[0][0][rr], m1 = redmx[1][0][rr];
        #pragma unroll
        for (int w = 1; w < 16; ++w) {
            m0 = fmaxf(m0, redmx[0][w][rr]);
            m1 = fmaxf(m1, redmx[1][w][rr]);
        }
        mxs[r] = m0; mxc[r] = m1;
    }
    // ---- row sum ----
    float sms[4], smc[4];
    #pragma unroll
    for (int r = 0; r < 4; ++r) { sms[r] = 0.f; smc[r] = 0.f; }
    #pragma unroll
    for (int ps = 0; ps < 4; ++ps)
        #pragma unroll
        for (int r = 0; r < 4; ++r) {
            sms[r] += expf(unpk(pS[ps][r >> 1], r & 1) - mxs[r]);
            smc[r] += expf(unpk(pC[ps][r >> 1], r & 1) - mxc[r]);
        }
    #pragma unroll
    for (int d = 1; d < 16; d <<= 1)
        #pragma unroll
        for (int r = 0; r < 4; ++r) {
            sms[r] += __shfl_xor(sms[r], d);
            smc[r] += __shfl_xor(smc[r], d);
        }
    if (lrow == 0)
        #pragma unroll
        for (int r = 0; r < 4; ++r) {
            redsm[0][wave][quad * 4 + r] = sms[r];
            redsm[1][wave][quad * 4 + r] = smc[r];
        }
    __syncthreads();
    float wgs[4], wgc[4];
    #pragma unroll
    for (int r = 0; r < 4; ++r) {
        int rr = quad * 4 + r;
        float d0 = redsm[0][0][rr], d1 = redsm[1][0][rr];
        #pragma unroll
        for (int w = 1; w < 16; ++w) {
            d0 += redsm[0][w][rr];
            d1 += redsm[1][w][rr];
        }
        wgs[r] = gr[r] / fmaxf(d0, 1e-30f);
        wgc[r] = gr[r] / fmaxf(d1, 1e-30f);
    }
    // ---- gated column accumulation ----
    #pragma unroll
    for (int ps = 0; ps < 4; ++ps) {
        int pr = (ps >> 1) * 32 + wave * 2 + (ps & 1);
        if (pr < npairs) {
            float as = 0.f, ar = 0.f;
            #pragma unroll
            for (int r = 0; r < 4; ++r) {
                as += wgs[r] * expf(unpk(pS[ps][r >> 1], r & 1) - mxs[r]);
                ar += wgc[r] * expf(unpk(pC[ps][r >> 1], r & 1) - mxc[r]);
            }
            as += __shfl_xor(as, 16); as += __shfl_xor(as, 32);
            ar += __shfl_xor(ar, 16); ar += __shfl_xor(ar, 32);
            if (quad == 0) {
                int m = msta + (pr >> 3) * 128 + (pr & 7) * 16 + lrow;
                atomicAdd(&csup[b * L + m], as);
                atomicAdd(&crep[b * L + m], ar);
            }
        }
    }
}

// ---------------- K3: af/w_rep/w_sup weighted sums over xb (bf16) ----------------
__global__ __launch_bounds__(256) void k3(const u16* __restrict__ xb,
        const float* __restrict__ gate, const float* __restrict__ csup,
        const float* __restrict__ crep, float* __restrict__ af,
        float* __restrict__ wrep, float* __restrict__ wsup) {
    int b = blockIdx.y, c = blockIdx.x;
    int tid = threadIdx.x;
    float a0 = 0.f, a1 = 0.f, a2 = 0.f;
    float r0 = 0.f, r1 = 0.f, r2 = 0.f;
    float q0 = 0.f, q1 = 0.f, q2 = 0.f;
    for (int mm = 0; mm < 16; ++mm) {
        int m = c * 16 + mm;
        float wg = gate[b * L + m], wr = crep[b * L + m], wq = csup[b * L + m];
        if (wg == 0.f && wr == 0.f && wq == 0.f) continue;
        size_t base = ((size_t)b * L + m) * D;
        float x0 = b2f(xb[base + tid]);
        float x1 = b2f(xb[base + tid + 256]);
        float x2 = b2f(xb[base + tid + 512]);
        a0 += wg * x0; a1 += wg * x1; a2 += wg * x2;
        r0 += wr * x0; r1 += wr * x1; r2 += wr * x2;
        q0 += wq * x0; q1 += wq * x1; q2 += wq * x2;
    }
    atomicAdd(&af[b * D + tid], a0); atomicAdd(&af[b * D + tid + 256], a1); atomicAdd(&af[b * D + tid + 512], a2);
    atomicAdd(&wrep[b * D + tid], r0); atomicAdd(&wrep[b * D + tid + 256], r1); atomicAdd(&wrep[b * D + tid + 512], r2);
    atomicAdd(&wsup[b * D + tid], q0); atomicAdd(&wsup[b * D + tid + 256], q1); atomicAdd(&wsup[b * D + tid + 512], q2);
}

// ---------------- kh1: hacc += fused @ Wf1 (split-K) ----------------
template<int F32> __device__ void kh1_body(const float* af, const float* wrep,
        const float* wsup, const void* Wf1, float* hacc, float* fs) {
    int tid = threadIdx.x;
    int c0 = blockIdx.x * 128, k0 = blockIdx.y * 144;
    for (int e = tid; e < 8 * 144; e += 256) {
        int b = e / 144, kk = e - b * 144;
        int k = k0 + kk;
        float v = (k < D) ? af[b * D + k] : (k < 2 * D) ? wrep[b * D + k - D]
                                                        : wsup[b * D + k - 2 * D];
        fs[b * 144 + kk] = v;
    }
    __syncthreads();
    int col = c0 + (tid & 127);
    int kg = tid >> 7;
    float acc[NB];
    #pragma unroll
    for (int b = 0; b < NB; ++b) acc[b] = 0.f;
    #pragma unroll 4
    for (int r = 0; r < 72; ++r) {
        int kk = kg * 72 + r;
        float w = ld1<F32>(Wf1, (size_t)(k0 + kk) * D + col);
        #pragma unroll
        for (int b = 0; b < NB; ++b) acc[b] += fs[b * 144 + kk] * w;
    }
    #pragma unroll
    for (int b = 0; b < NB; ++b) atomicAdd(&hacc[b * D + col], acc[b]);
}
__global__ __launch_bounds__(256) void kh1(const void* x, const int* ids,
        const float* af, const float* wrep,
        const float* wsup, const void* Wf1, float* hacc) {
    __shared__ float fs[8 * 144];
    __shared__ int fsh[2];
    detect2(x, ids, fsh);
    if (fsh[0]) kh1_body<1>(af, wrep, wsup, Wf1, hacc, fs);
    else        kh1_body<0>(af, wrep, wsup, Wf1, hacc, fs);
}

// ---------------- kh2: oacc += relu(hacc+bf1) @ Wf2 (split-K) ----------------
template<int F32> __device__ void kh2_body(const float* hacc, const void* bf1,
        const void* Wf2, float* oacc, float* hsl) {
    int tid = threadIdx.x;
    int c0 = blockIdx.x * 128, k0 = blockIdx.y * 96;
    for (int e = tid; e < 8 * 96; e += 256) {
        int b = e / 96, kk = e - b * 96;
        int k = k0 + kk;
        hsl[b * 96 + kk] = fmaxf(hacc[b * D + k] + ld1<F32>(bf1, k), 0.f);
    }
    __syncthreads();
    int col = c0 + (tid & 127);
    int kg = tid >> 7;
    float acc[NB];
    #pragma unroll
    for (int b = 0; b < NB; ++b) acc[b] = 0.f;
    #pragma unroll 4
    for (int r = 0; r < 48; ++r) {
        int kk = kg * 48 + r;
        float w = ld1<F32>(Wf2, (size_t)(k0 + kk) * D + col);
        #pragma unroll
        for (int b = 0; b < NB; ++b) acc[b] += hsl[b * 96 + kk] * w;
    }
    #pragma unroll
    for (int b = 0; b < NB; ++b) atomicAdd(&oacc[b * D + col], acc[b]);
}
__global__ __launch_bounds__(256) void kh2(const void* x, const int* ids,
        const float* hacc, const void* bf1,
        const void* Wf2, float* oacc) {
    __shared__ float hsl[8 * 96];
    __shared__ int fsh[2];
    detect2(x, ids, fsh);
    if (fsh[0]) kh2_body<1>(hacc, bf1, Wf2, oacc, hsl);
    else        kh2_body<0>(hacc, bf1, Wf2, oacc, hsl);
}

// ---------------- kln: out = LN(oacc + bf2) * gamma + beta ----------------
template<int F32> __device__ void kln_body(const float* oacc, const void* bf2,
        const void* gamma, const void* beta, void* out, float* red) {
    int b = blockIdx.x, tid = threadIdx.x;
    float o[3];
    #pragma unroll
    for (int u = 0; u < 3; ++u) {
        int i = tid + u * 256;
        o[u] = oacc[b * D + i] + ld1<F32>(bf2, i);
    }
    red[tid] = o[0] + o[1] + o[2]; __syncthreads();
    for (int s = 128; s > 0; s >>= 1) { if (tid < s) red[tid] += red[tid + s]; __syncthreads(); }
    float mu = red[0] / (float)D; __syncthreads();
    float vs = 0.f;
    #pragma unroll
    for (int u = 0; u < 3; ++u) vs += (o[u] - mu) * (o[u] - mu);
    red[tid] = vs; __syncthreads();
    for (int s = 128; s > 0; s >>= 1) { if (tid < s) red[tid] += red[tid + s]; __syncthreads(); }
    float var = red[0] / (float)D;
    float rstd = 1.0f / sqrtf(var + 1e-5f);
    #pragma unroll
    for (int u = 0; u < 3; ++u) {
        int i = tid + u * 256;
        float v = (o[u] - mu) * rstd * ld1<F32>(gamma, i) + ld1<F32>(beta, i);
        if (F32) ((float*)out)[b * D + i] = v;
        else     ((u16*)out)[b * D + i] = f2b(v);
    }
}
__global__ __launch_bounds__(256) void kln(const void* x, const int* ids,
        const float* oacc, const void* bf2,
        const void* gamma, const void* beta, void* out) {
    __shared__ float red[256];
    __shared__ int fsh[2];
    detect2(x, ids, fsh);
    if (fsh[0]) kln_body<1>(oacc, bf2, gamma, beta, out, red);
    else        kln_body<0>(oacc, bf2, gamma, beta, out, red);
}

extern "C" void kernel_launch(void* const* d_in, const int* in_sizes, int n_in,
                              void* d_out, int out_size, void* d_ws, size_t ws_size,
                              hipStream_t stream) {
    const void* x    = d_in[0];
    const int* ids   = (const int*)d_in[1];
    const int* padp  = (const int*)d_in[2];
    const void* Wa   = d_in[3];
    const void* ba   = d_in[4];
    PP pp;
    pp.W[0] = d_in[5];  pp.b[0] = d_in[6];    // qs
    pp.W[1] = d_in[7];  pp.b[1] = d_in[8];    // ks
    pp.W[2] = d_in[9];  pp.b[2] = d_in[10];   // qc
    pp.W[3] = d_in[11]; pp.b[3] = d_in[12];   // kc
    pp.W[4] = d_in[13]; pp.b[4] = d_in[14];   // qr
    pp.W[5] = d_in[15]; pp.b[5] = d_in[16];   // kr
    const void* Wf1 = d_in[17]; const void* bf1 = d_in[18];
    const void* Wf2 = d_in[19]; const void* bf2 = d_in[20];
    const void* gamma = d_in[21]; const void* beta = d_in[22];

    char* ws = (char*)d_ws;
    int*   sepArr = (int*)(ws + WS_SEP);
    float* c0   = (float*)(ws + WS_C0);
    float* z0   = (float*)(ws + WS_Z0);
    float* w1   = (float*)(ws + WS_W1);
    float* gate = (float*)(ws + WS_GATE);
    float* csup = (float*)(ws + WS_CSUP);
    float* crep = (float*)(ws + WS_CREP);
    float* af   = (float*)(ws + WS_AF);
    float* wrep = (float*)(ws + WS_WREP);
    float* wsup = (float*)(ws + WS_WSUP);
    float* hacc = (float*)(ws + WS_HACC);
    float* oacc = (float*)(ws + WS_OACC);
    float* alog = (float*)(ws + WS_ALOG);
    float* tbuf = (float*)(ws + WS_T);
    u16* xb   = (u16*)(ws + WS_XB);
    u16* Zbuf = (u16*)(ws + WS_Z);
    u16* Wb   = (u16*)(ws + WS_WB);
    u16* Mt   = (u16*)(ws + WS_M);

    kx<<<dim3(2044), dim3(256), 0, stream>>>(x, ids, pp, Wa, ba, xb, Wb, alog, z0, w1, c0);
    kB<<<dim3(256), dim3(256), 0, stream>>>(x, ids, padp, alog, gate, sepArr,
                                            af, wrep, wsup, hacc, oacc, csup, crep,
                                            xb, w1, c0, tbuf, Wb, Mt);
    kZ_mfma<<<dim3(6, 4, 24), dim3(256), 0, stream>>>(xb, Mt, z0, Zbuf, sepArr);
    kS2<<<dim3(256), dim3(1024), 0, stream>>>(Zbuf, xb, tbuf, sepArr, ids, padp,
                                              gate, csup, crep);
    k3<<<dim3(64, NB), dim3(256), 0, stream>>>(xb, gate, csup, crep, af, wrep, wsup);
    kh1<<<dim3(6, 16), dim3(256), 0, stream>>>(x, ids, af, wrep, wsup, Wf1, hacc);
    kh2<<<dim3(6, 8), dim3(256), 0, stream>>>(x, ids, hacc, bf1, Wf2, oacc);
    kln<<<dim3(NB), dim3(256), 0, stream>>>(x, ids, oacc, bf2, gamma, beta, d_out);
}

// Round 12
// 250.618 us; speedup vs baseline: 1.0792x; 1.0792x over previous
//
#include <hip/hip_runtime.h>
#include <math.h>

#define L 1024
#define NB 8
#define D 768
#define NEGV (-9.0e15f)
#define SCALE 0.036084391824351615f  // 1/sqrt(768)

typedef unsigned short u16;
typedef __attribute__((ext_vector_type(8))) short short8;
typedef __attribute__((ext_vector_type(4))) float float4v;
#define MFMA_BF16 __builtin_amdgcn_mfma_f32_16x16x32_bf16

__device__ __forceinline__ float b2f(u16 u) {
    union { unsigned int i; float f; } v; v.i = ((unsigned int)u) << 16; return v.f;
}
__device__ __forceinline__ u16 f2b(float f) {
    union { float fv; unsigned int i; } v; v.fv = f;
    unsigned int x = v.i;
    x += 0x7fffu + ((x >> 16) & 1u);   // RNE
    return (u16)(x >> 16);
}
__device__ __forceinline__ float unpk(unsigned int w, int h) {
    return b2f((u16)(h ? (w >> 16) : (w & 0xffffu)));
}

template<int F32>
__device__ __forceinline__ float4 ld4(const void* p, size_t idx) {
    if (F32) return *(const float4*)((const float*)p + idx);
    ushort4 v = *(const ushort4*)((const u16*)p + idx);
    return make_float4(b2f(v.x), b2f(v.y), b2f(v.z), b2f(v.w));
}
template<int F32>
__device__ __forceinline__ float ld1(const void* p, size_t idx) {
    if (F32) return ((const float*)p)[idx];
    return b2f(((const u16*)p)[idx]);
}
__device__ __forceinline__ int ldid(const int* p, size_t idx, int is64) {
    return is64 ? p[idx * 2] : p[idx];
}

// inline dtype detection: sh[0]=1 if floats are f32, sh[1]=1 if ids are int64.
__device__ __forceinline__ void detect2(const void* x, const void* ids, int* sh) {
    int tid = threadIdx.x;
    if (tid < 64) {
        u16 u = ((const u16*)x)[tid * 2];
        int e = (u >> 7) & 0xFF;
        unsigned long long balf = __ballot(e >= 100 && e <= 140);
        int v = ((const int*)ids)[tid * 2 + 1];
        unsigned long long bali = __ballot(v != 0);
        if (tid == 0) {
            sh[0] = (__popcll(balf) < 32) ? 1 : 0;
            sh[1] = (bali == 0ULL) ? 1 : 0;
        }
    }
    __syncthreads();
}

// ---------------- workspace layout (bytes) ----------------
#define WS_FLAG  ((size_t)0)
#define WS_SEP   ((size_t)64)
#define WS_C0    ((size_t)128)
#define WS_Z0    ((size_t)192)
#define WS_W1    ((size_t)9472)
#define WS_GATE  ((size_t)18752)
#define WS_CSUP  ((size_t)51520)
#define WS_CREP  ((size_t)84288)
#define WS_AF    ((size_t)117056)
#define WS_WREP  ((size_t)141632)
#define WS_WSUP  ((size_t)166208)
#define WS_HACC  ((size_t)190784)
#define WS_ALOG  ((size_t)215360)
#define WS_T     ((size_t)248128)
#define WS_OACC  ((size_t)303104)
#define WS_XB    ((size_t)524288)
#define WS_Z     ((size_t)13107200)
#define WS_WB    ((size_t)31981568)   // 6*D*D bf16
#define WS_M     ((size_t)40370176)   // 3*D*D bf16

struct PP { const void* W[6]; const void* b[6]; };

// ---------------- bias bodies ----------------
template<int F32> __device__ void kbias_body(const void* W, const void* vec,
        float* out, float* vs, int xi) {
    int tid = threadIdx.x;
    for (int i = tid; i < D; i += 256) vs[i] = ld1<F32>(vec, i);
    __syncthreads();
    int row = xi * 64 + (tid >> 2);
    int sub = tid & 3;
    float acc = 0.f;
    for (int i = 0; i < 48; ++i) {
        int k = i * 16 + sub * 4;
        float4 wv = ld4<F32>(W, (size_t)row * D + k);
        acc += wv.x * vs[k] + wv.y * vs[k + 1] + wv.z * vs[k + 2] + wv.w * vs[k + 3];
    }
    acc += __shfl_xor(acc, 1);
    acc += __shfl_xor(acc, 2);
    if (sub == 0) out[row] = acc;
}
template<int F32> __device__ void kc0_body(const void* bq, const void* bk,
        float* c0, float* red) {
    int tid = threadIdx.x;
    float s = 0.f;
    for (int i = tid; i < D; i += 256) s += ld1<F32>(bq, i) * ld1<F32>(bk, i);
    red[tid] = s; __syncthreads();
    for (int st = 128; st > 0; st >>= 1) { if (tid < st) red[tid] += red[tid + st]; __syncthreads(); }
    if (tid == 0) c0[0] = red[0];
}

// ---------------- kx: fused x->bf16 + Wa row-dot + W->bf16 + bias rows ----------------
template<int F32> __device__ void kx_body(const void* x, const void* Wa,
        const void* ba, u16* xb, float* alog, float* ws2) {
    int tid = threadIdx.x;
    for (int i = tid; i < D; i += 256) ws2[i] = ld1<F32>(Wa, i);
    __syncthreads();
    int row = blockIdx.x * 32 + (tid >> 3);
    int sub = tid & 7;
    float a0 = 0.f;
    for (int i = 0; i < 24; ++i) {
        int k = i * 32 + sub * 4;
        float4 xv = ld4<F32>(x, (size_t)row * D + k);
        ushort4 o;
        o.x = f2b(xv.x); o.y = f2b(xv.y); o.z = f2b(xv.z); o.w = f2b(xv.w);
        *(ushort4*)(xb + (size_t)row * D + k) = o;
        a0 += xv.x * ws2[k] + xv.y * ws2[k + 1] + xv.z * ws2[k + 2] + xv.w * ws2[k + 3];
    }
    #pragma unroll
    for (int d = 1; d < 8; d <<= 1) a0 += __shfl_xor(a0, d);
    if (sub == 0) alog[row] = a0 + ld1<F32>(ba, 0);
}
__global__ __launch_bounds__(256) void kx(const void* x, const int* ids, PP pp,
        const void* Wa, const void* ba, u16* xb, u16* Wb, float* alog,
        float* z0, float* w1, float* c0f) {
    __shared__ float sf[2 * D];
    __shared__ int fsh[2];
    detect2(x, ids, fsh);
    int F32 = fsh[0];
    int bid = blockIdx.x;
    if (bid < 256) {
        if (F32) kx_body<1>(x, Wa, ba, xb, alog, sf);
        else     kx_body<0>(x, Wa, ba, xb, alog, sf);
        return;
    }
    if (bid < 1984) {
        int t = (bid - 256) / 288, inner = (bid - 256) % 288;
        const void* src = pp.W[t];
        u16* dst = Wb + (size_t)t * D * D;
        size_t base = ((size_t)inner * 256 + threadIdx.x) * 8;
        if (F32) {
            float4 a = *(const float4*)((const float*)src + base);
            float4 b = *(const float4*)((const float*)src + base + 4);
            uint4 o; u16* po = (u16*)&o;
            po[0] = f2b(a.x); po[1] = f2b(a.y); po[2] = f2b(a.z); po[3] = f2b(a.w);
            po[4] = f2b(b.x); po[5] = f2b(b.y); po[6] = f2b(b.z); po[7] = f2b(b.w);
            *(uint4*)(dst + base) = o;
        } else {
            *(uint4*)(dst + base) = *(const uint4*)((const u16*)src + base);
        }
        return;
    }
    int i = bid - 1984;            // 0..59
    int y = i / 12, xi = i % 12;
    float* vs = sf;
    float* red = sf + D;
    if (y == 4) {
        if (xi != 0) return;
        if (F32) kc0_body<1>(pp.b[2], pp.b[3], c0f, red);
        else     kc0_body<0>(pp.b[2], pp.b[3], c0f, red);
        return;
    }
    const void* W; const void* vec; float* out;
    if (y < 3) { W = pp.W[2 * y + 1]; vec = pp.b[2 * y]; out = z0 + y * D; }
    else       { W = pp.W[2];         vec = pp.b[3];     out = w1; }
    if (F32) kbias_body<1>(W, vec, out, vs, xi);
    else     kbias_body<0>(W, vec, out, vs, xi);
}

// ================= staging with involutory col-block swizzle =================
__device__ __forceinline__ void stage128_async(const u16* __restrict__ G, size_t ld,
        int r0, int k0, u16* S, int tid) {
    int rowa = tid >> 2;
    int koa = ((tid & 3) ^ (rowa & 3)) << 3;
    int wave = tid >> 6;
    const u16* g1 = &G[(size_t)(r0 + rowa) * ld + k0 + koa];
    const u16* g2 = &G[(size_t)(r0 + rowa + 64) * ld + k0 + koa];
    __builtin_amdgcn_global_load_lds((__attribute__((address_space(1))) void*)(u16*)g1,
        (__attribute__((address_space(3))) void*)(S + wave * 512), 16, 0, 0);
    __builtin_amdgcn_global_load_lds((__attribute__((address_space(1))) void*)(u16*)g2,
        (__attribute__((address_space(3))) void*)(S + 2048 + wave * 512), 16, 0, 0);
}
__device__ __forceinline__ void stage64_async(const u16* __restrict__ G, size_t ld,
        int r0, int k0, u16* S, int tid) {
    int rowa = tid >> 2;
    int koa = ((tid & 3) ^ (rowa & 3)) << 3;
    int wave = tid >> 6;
    const u16* g = &G[(size_t)(r0 + rowa) * ld + k0 + koa];
    __builtin_amdgcn_global_load_lds((__attribute__((address_space(1))) void*)(u16*)g,
        (__attribute__((address_space(3))) void*)(S + wave * 512), 16, 0, 0);
}

// ============ counted-vmcnt 2-buffer GEMM cores ============
// BM=64, BN=128, K=768. As: 2x4096 u16 (16KB), Bs: 2x8192 u16 (32KB). 6 loads/iter.
__device__ __forceinline__ void gemm64_cnt(const u16* __restrict__ A, size_t lda, int r0,
        const u16* __restrict__ B, size_t ldb, int c0,
        u16* As, u16* Bs, float4v acc[2][4]) {
    int tid = threadIdx.x;
    int lane = tid & 63, wave = tid >> 6;
    int wm = (wave >> 1) << 5, wn = (wave & 1) << 6;
    int quad = lane >> 4, lrow = lane & 15;
    int sq = ((quad ^ (lrow & 3)) << 3);
    #pragma unroll
    for (int i = 0; i < 2; ++i)
        #pragma unroll
        for (int j = 0; j < 4; ++j) acc[i][j] = (float4v){0.f, 0.f, 0.f, 0.f};
    stage64_async(A, lda, r0, 0, As, tid);
    stage64_async(A, lda, r0, 32, As + 2048, tid);
    stage128_async(B, ldb, c0, 0, Bs, tid);
    stage128_async(B, ldb, c0, 32, Bs + 4096, tid);
    stage64_async(A, lda, r0, 64, As + 4096, tid);
    stage64_async(A, lda, r0, 96, As + 6144, tid);
    stage128_async(B, ldb, c0, 64, Bs + 8192, tid);
    stage128_async(B, ldb, c0, 96, Bs + 12288, tid);
    #pragma unroll 1
    for (int t = 0; t < 12; ++t) {
        int cur = t & 1;
        if (t != 11) asm volatile("s_waitcnt vmcnt(6)" ::: "memory");
        else         asm volatile("s_waitcnt vmcnt(0)" ::: "memory");
        __builtin_amdgcn_s_barrier();
        const u16* Ab = As + cur * 4096;
        const u16* Bb = Bs + cur * 8192;
        short8 fa[2][2], fb[2][4];
        #pragma unroll
        for (int p = 0; p < 2; ++p) {
            #pragma unroll
            for (int i = 0; i < 2; ++i)
                fa[p][i] = *(const short8*)&Ab[p * 2048 + (wm + i * 16 + lrow) * 32 + sq];
            #pragma unroll
            for (int j = 0; j < 4; ++j)
                fb[p][j] = *(const short8*)&Bb[p * 4096 + (wn + j * 16 + lrow) * 32 + sq];
        }
        asm volatile("s_waitcnt lgkmcnt(0)" ::: "memory");
        __builtin_amdgcn_sched_barrier(0);
        __builtin_amdgcn_s_barrier();
        if (t < 10) {
            int k0 = (t + 2) << 6;
            u16* Ad = As + cur * 4096;
            u16* Bd = Bs + cur * 8192;
            stage64_async(A, lda, r0, k0, Ad, tid);
            stage64_async(A, lda, r0, k0 + 32, Ad + 2048, tid);
            stage128_async(B, ldb, c0, k0, Bd, tid);
            stage128_async(B, ldb, c0, k0 + 32, Bd + 4096, tid);
        }
        #pragma unroll
        for (int p = 0; p < 2; ++p)
            #pragma unroll
            for (int i = 0; i < 2; ++i)
                #pragma unroll
                for (int j = 0; j < 4; ++j)
                    acc[i][j] = MFMA_BF16(fa[p][i], fb[p][j], acc[i][j], 0, 0, 0);
    }
}

// BM=128, BN=128. As: 2x8192 u16 (32KB), Bs: 2x8192 u16 (32KB). 8 loads/iter.
__device__ __forceinline__ void gemm128_cnt(const u16* __restrict__ A, size_t lda, int r0,
        const u16* __restrict__ B, size_t ldb, int c0,
        u16* As, u16* Bs, float4v acc[4][4]) {
    int tid = threadIdx.x;
    int lane = tid & 63, wave = tid >> 6;
    int wm = (wave >> 1) << 6, wn = (wave & 1) << 6;
    int quad = lane >> 4, lrow = lane & 15;
    int sq = ((quad ^ (lrow & 3)) << 3);
    #pragma unroll
    for (int i = 0; i < 4; ++i)
        #pragma unroll
        for (int j = 0; j < 4; ++j) acc[i][j] = (float4v){0.f, 0.f, 0.f, 0.f};
    stage128_async(A, lda, r0, 0, As, tid);
    stage128_async(A, lda, r0, 32, As + 4096, tid);
    stage128_async(B, ldb, c0, 0, Bs, tid);
    stage128_async(B, ldb, c0, 32, Bs + 4096, tid);
    stage128_async(A, lda, r0, 64, As + 8192, tid);
    stage128_async(A, lda, r0, 96, As + 12288, tid);
    stage128_async(B, ldb, c0, 64, Bs + 8192, tid);
    stage128_async(B, ldb, c0, 96, Bs + 12288, tid);
    #pragma unroll 1
    for (int t = 0; t < 12; ++t) {
        int cur = t & 1;
        if (t != 11) asm volatile("s_waitcnt vmcnt(8)" ::: "memory");
        else         asm volatile("s_waitcnt vmcnt(0)" ::: "memory");
        __builtin_amdgcn_s_barrier();
        const u16* Ab = As + cur * 8192;
        const u16* Bb = Bs + cur * 8192;
        short8 fa[2][4], fb[2][4];
        #pragma unroll
        for (int p = 0; p < 2; ++p) {
            #pragma unroll
            for (int i = 0; i < 4; ++i)
                fa[p][i] = *(const short8*)&Ab[p * 4096 + (wm + i * 16 + lrow) * 32 + sq];
            #pragma unroll
            for (int j = 0; j < 4; ++j)
                fb[p][j] = *(const short8*)&Bb[p * 4096 + (wn + j * 16 + lrow) * 32 + sq];
        }
        asm volatile("s_waitcnt lgkmcnt(0)" ::: "memory");
        __builtin_amdgcn_sched_barrier(0);
        __builtin_amdgcn_s_barrier();
        if (t < 10) {
            int k0 = (t + 2) << 6;
            u16* Ad = As + cur * 8192;
            u16* Bd = Bs + cur * 8192;
            stage128_async(A, lda, r0, k0, Ad, tid);
            stage128_async(A, lda, r0, k0 + 32, Ad + 4096, tid);
            stage128_async(B, ldb, c0, k0, Bd, tid);
            stage128_async(B, ldb, c0, k0 + 32, Bd + 4096, tid);
        }
        #pragma unroll
        for (int p = 0; p < 2; ++p)
            #pragma unroll
            for (int i = 0; i < 4; ++i)
                #pragma unroll
                for (int j = 0; j < 4; ++j)
                    acc[i][j] = MFMA_BF16(fa[p][i], fb[p][j], acc[i][j], 0, 0, 0);
    }
}

// ---------------- kB: blocks 0..7 gate/sep/zero; 8..223 kM; 224..255 tbuf ----------------
__global__ __launch_bounds__(256) void kB(const void* x, const int* __restrict__ ids,
        const int* __restrict__ padp, const float* __restrict__ alog,
        float* __restrict__ gate, int* __restrict__ sepArr,
        float* __restrict__ af, float* __restrict__ wrep, float* __restrict__ wsup,
        float* __restrict__ hacc, float* __restrict__ oacc,
        float* __restrict__ csup, float* __restrict__ crep,
        const u16* __restrict__ xb, const float* __restrict__ w1,
        const float* __restrict__ c0f, float* __restrict__ tbuf,
        const u16* __restrict__ Wb, u16* __restrict__ Mt) {
    __shared__ __align__(16) u16 SMEM[24576];   // 48 KB
    int bid = blockIdx.x;
    int tid = threadIdx.x;
    if (bid >= 8 && bid < 224) {
        int i = bid - 8;
        int p = i / 72, j = i % 72;
        int r0 = (j / 6) * 64, c0m = (j % 6) * 128;
        u16* As = SMEM;
        u16* Bs = SMEM + 8192;
        float4v acc[2][4];
        gemm64_cnt(Wb + (size_t)(2 * p + 1) * D * D, D, r0,
                   Wb + (size_t)(2 * p) * D * D, D, c0m, As, Bs, acc);
        int lane = tid & 63, wave = tid >> 6;
        int wm = (wave >> 1) << 5, wn = (wave & 1) << 6;
        int quad = lane >> 4, lrow = lane & 15;
        u16* out = Mt + (size_t)p * D * D;
        #pragma unroll
        for (int ii = 0; ii < 2; ++ii)
            #pragma unroll
            for (int jj = 0; jj < 4; ++jj) {
                int brow = r0 + wm + ii * 16 + quad * 4;
                int col = c0m + wn + jj * 16 + lrow;
                #pragma unroll
                for (int r = 0; r < 4; ++r)
                    out[(size_t)(brow + r) * D + col] = f2b(acc[ii][jj][r]);
            }
        return;
    }
    if (bid >= 224) {
        int i = bid - 224;
        int b = i >> 2, q = i & 3;
        float* w1s = (float*)SMEM;
        for (int j = tid; j < D; j += 256) w1s[j] = w1[j];
        __syncthreads();
        float c0v = c0f[0];
        int sub = tid & 15;
        int rowi = tid >> 4;
        for (int pass = 0; pass < 8; ++pass) {
            int l = q * 128 + pass * 16 + rowi;
            const u16* xr = xb + ((size_t)b * L + l) * D;
            float a = 0.f;
            #pragma unroll
            for (int i2 = 0; i2 < 6; ++i2) {
                int k = i2 * 128 + sub * 8;
                short8 v = *(const short8*)&xr[k];
                #pragma unroll
                for (int e = 0; e < 8; ++e) a += b2f((u16)v[e]) * w1s[k + e];
            }
            #pragma unroll
            for (int d2 = 1; d2 < 16; d2 <<= 1) a += __shfl_xor(a, d2);
            if (sub == 0) tbuf[b * 512 + l] = a + c0v;
        }
        return;
    }
    // --- gate/sep/zero (blocks 0..7) ---
    float* red = (float*)SMEM;
    int*   ish = (int*)(red + 256);
    detect2(x, ids, ish);
    int is64 = ish[1];
    int b = bid;
    int pad = padp[0];
    int cnt = 0;
    for (int l = tid; l < L; l += 256) cnt += (ldid(ids, (size_t)b * L + l, is64) != pad) ? 1 : 0;
    red[tid] = (float)cnt; __syncthreads();
    for (int s = 128; s > 0; s >>= 1) { if (tid < s) red[tid] += red[tid + s]; __syncthreads(); }
    if (tid == 0) {
        int vl = (int)red[0];
        int sep = vl / 2; if (sep < 1) sep = 1; if (sep > L - 2) sep = L - 2;
        ish[2] = sep; sepArr[b] = sep;
    }
    __syncthreads();
    int sep = ish[2];
    float lv[4]; int lidx[4];
    float mx = -3.4e38f;
    for (int u = 0; u < 4; ++u) {
        int l = tid + u * 256; lidx[u] = l;
        bool fm = (l < sep) && (ldid(ids, (size_t)b * L + l, is64) != pad);
        float v = fm ? alog[b * L + l] : NEGV;
        lv[u] = v; mx = fmaxf(mx, v);
    }
    red[tid] = mx; __syncthreads();
    for (int s = 128; s > 0; s >>= 1) { if (tid < s) red[tid] = fmaxf(red[tid], red[tid + s]); __syncthreads(); }
    mx = red[0]; __syncthreads();
    float se = 0.f;
    for (int u = 0; u < 4; ++u) { lv[u] = expf(lv[u] - mx); se += lv[u]; }
    red[tid] = se; __syncthreads();
    for (int s = 128; s > 0; s >>= 1) { if (tid < s) red[tid] += red[tid + s]; __syncthreads(); }
    float den = fmaxf(red[0], 1e-30f); __syncthreads();
    float gs = 0.f; float gv[4];
    for (int u = 0; u < 4; ++u) {
        int l = lidx[u];
        bool fm = (l < sep) && (ldid(ids, (size_t)b * L + l, is64) != pad);
        float p = lv[u] / den;
        gv[u] = fm ? p : 0.f;
        gs += gv[u];
    }
    red[tid] = gs; __syncthreads();
    for (int s = 128; s > 0; s >>= 1) { if (tid < s) red[tid] += red[tid + s]; __syncthreads(); }
    gs = red[0];
    float inv = 1.f / fmaxf(gs, 1e-8f);
    for (int u = 0; u < 4; ++u) gate[b * L + lidx[u]] = gv[u] * inv;
    for (int l = tid; l < L; l += 256) { csup[b * L + l] = 0.f; crep[b * L + l] = 0.f; }
    for (int i = tid; i < D; i += 256) {
        af[b * D + i] = 0.f; wrep[b * D + i] = 0.f; wsup[b * D + i] = 0.f;
        hacc[b * D + i] = 0.f; oacc[b * D + i] = 0.f;
    }
}

// ---------------- kZ: Z[l][j] = sum_k xb[l][k] Mt[j][k] + z0[j] ----------------
__global__ __launch_bounds__(256) void kZ_mfma(const u16* __restrict__ xb,
        const u16* __restrict__ Mt, const float* __restrict__ z0,
        u16* __restrict__ Zbuf, const int* __restrict__ sepArr) {
    __shared__ __align__(16) u16 As[16384];
    __shared__ __align__(16) u16 Bs[16384];
    int z = blockIdx.z;
    int p = z >> 3, b = z & 7;
    int sep = sepArr[b];
    int r0 = blockIdx.y * 128;
    if (r0 >= sep) return;
    int c0 = blockIdx.x * 128;
    float4v acc[4][4];
    gemm128_cnt(xb + (size_t)b * L * D, D, r0,
                Mt + (size_t)p * D * D, D, c0, As, Bs, acc);
    int lane = threadIdx.x & 63, wave = threadIdx.x >> 6;
    int wm = (wave >> 1) << 6, wn = (wave & 1) << 6;
    int quad = lane >> 4, lrow = lane & 15;
    const float* z0p = z0 + p * D;
    u16* out = Zbuf + ((size_t)p * NB + b) * 512 * D;
    #pragma unroll
    for (int i = 0; i < 4; ++i)
        #pragma unroll
        for (int j = 0; j < 4; ++j) {
            int brow = r0 + wm + i * 16 + quad * 4;
            int col = c0 + wn + j * 16 + lrow;
            float zb = z0p[col];
            #pragma unroll
            for (int r = 0; r < 4; ++r)
                out[(size_t)(brow + r) * D + col] = f2b(acc[i][j][r] + zb);
        }
}

// ---------------- kS2: con/rep A in LDS (49KB, staged once) + sup A & B register-direct ----------------
// 256 blocks x 512 threads, b = bid&7 (XCD alignment), 16 Q-rows per block.
// con+rep A (2 mats x 16 rows x 768) staged ONCE into 49.2KB LDS with per-row
// XOR slot swizzle; sup A and 4 B columns loaded via asm global_load_dwordx4
// in a 3-deep rotation (5 loads/step, 15 in flight, vmcnt(10)+sched_barrier).
// No barriers inside the K-loop. Static LDS kept < 64KB.
__global__ __launch_bounds__(512) void kS2(const u16* __restrict__ Zbuf,
        const u16* __restrict__ xb, const float* __restrict__ tcbuf,
        const int* __restrict__ sepArr, const int* __restrict__ ids,
        const int* __restrict__ padp, const float* __restrict__ gate,
        float* __restrict__ csup, float* __restrict__ crep) {
    __shared__ __align__(16) u16 Alds[24576];   // 2 mats * 16 rows * 96 slots * 8 u16 = 49152 B
    __shared__ float redmx[2][8][16];
    __shared__ float redsm[2][8][16];
    __shared__ int ish[1];
    int bid = blockIdx.x;
    int b = bid & 7;
    int l0 = (bid >> 3) * 16;
    int sep = sepArr[b];
    int tid = threadIdx.x, lane = tid & 63, wave = tid >> 6;
    int lrow = lane & 15, quad = lane >> 4;
    if (tid < 64) {
        int v = ((const int*)ids)[tid * 2 + 1];
        unsigned long long bali = __ballot(v != 0);
        if (tid == 0) ish[0] = (bali == 0ULL) ? 1 : 0;
    }
    __syncthreads();
    if (l0 >= sep) return;      // block-uniform
    int is64 = ish[0];
    int pad = padp[0];
    int msta = ((sep + 1) >> 7) << 7;
    int nchunk = (L - msta) >> 7;
    const u16* A0 = Zbuf + (size_t)b * 512 * D;              // sup (register-direct)
    const u16* A1 = Zbuf + ((size_t)NB + b) * 512 * D;       // con -> LDS mat 0
    const u16* A2 = Zbuf + ((size_t)2 * NB + b) * 512 * D;   // rep -> LDS mat 1
    const u16* X  = xb + (size_t)b * L * D;
    // ---- stage con+rep once: slot s -> mat m, row r, col-slot c (16B each) ----
    #pragma unroll
    for (int i = 0; i < 6; ++i) {
        int s = tid + i * 512;           // 0..3071
        int m = s / 1536, rem = s - m * 1536;
        int r = rem / 96, c = rem - r * 96;
        const u16* src = (m == 0 ? A1 : A2) + (size_t)(l0 + r) * D + c * 8;
        *(short8*)&Alds[(((m * 16 + r) * 96) + (c ^ (r & 7))) * 8] = *(const short8*)src;
    }
    __syncthreads();
    float tcv[4], gr[4];
    #pragma unroll
    for (int r = 0; r < 4; ++r) {
        tcv[r] = tcbuf[b * 512 + l0 + quad * 4 + r];
        gr[r]  = gate[b * L + l0 + quad * 4 + r];
    }
    int xr = lrow & 7;
    int arow0 = lrow * 768;              // u16 index of row base (96 slots * 8)
    const u16* pA0_ = A0 + (size_t)(l0 + lrow) * D + quad * 8;
    unsigned int pS[8][2], pC[8][2];
    #pragma unroll
    for (int g = 0; g < 2; ++g) {
      if (g * 4 < nchunk) {
        const u16 *pB0_, *pB1_, *pB2_, *pB3_;
        {
            int m00 = msta + (g * 4 + 0) * 128; if (m00 > L - 128) m00 = L - 128;
            int m01 = msta + (g * 4 + 1) * 128; if (m01 > L - 128) m01 = L - 128;
            int m02 = msta + (g * 4 + 2) * 128; if (m02 > L - 128) m02 = L - 128;
            int m03 = msta + (g * 4 + 3) * 128; if (m03 > L - 128) m03 = L - 128;
            pB0_ = X + (size_t)(m00 + wave * 16 + lrow) * D + quad * 8;
            pB1_ = X + (size_t)(m01 + wave * 16 + lrow) * D + quad * 8;
            pB2_ = X + (size_t)(m02 + wave * 16 + lrow) * D + quad * 8;
            pB3_ = X + (size_t)(m03 + wave * 16 + lrow) * D + quad * 8;
        }
        float4v acc[3][4];
        #pragma unroll
        for (int m = 0; m < 3; ++m)
            #pragma unroll
            for (int cc = 0; cc < 4; ++cc) acc[m][cc] = (float4v){0.f, 0.f, 0.f, 0.f};
        short8 fA1, fA2;
        short8 A0a, B0a, B1a, B2a, B3a;
        short8 A0b, B0b, B1b, B2b, B3b;
        short8 A0c, B0c, B1c, B2c, B3c;
#define GL_(dst, base, imm) asm volatile("global_load_dwordx4 %0, %1, off offset:" #imm : "=v"(dst) : "v"(base))
#define GL(dst, base, imm) GL_(dst, base, imm)
#define LDG5(SUF, IMM) do { \
        GL(A0##SUF, pA0_, IMM); \
        GL(B0##SUF, pB0_, IMM); GL(B1##SUF, pB1_, IMM); \
        GL(B2##SUF, pB2_, IMM); GL(B3##SUF, pB3_, IMM); } while (0)
#define LDA(S) do { int sw = (((4 * (S) + quad) ^ xr) << 3); \
        fA1 = *(const short8*)&Alds[arow0 + sw]; \
        fA2 = *(const short8*)&Alds[12288 + arow0 + sw]; } while (0)
#define WAITN_(N) do { asm volatile("s_waitcnt vmcnt(" #N ")"); \
        __builtin_amdgcn_sched_barrier(0); } while (0)
#define WAITN(N) WAITN_(N)
#define CPSTEP(SUF) do { \
        acc[0][0] = MFMA_BF16(A0##SUF, B0##SUF, acc[0][0], 0, 0, 0); \
        acc[1][0] = MFMA_BF16(fA1, B0##SUF, acc[1][0], 0, 0, 0); \
        acc[2][0] = MFMA_BF16(fA2, B0##SUF, acc[2][0], 0, 0, 0); \
        acc[0][1] = MFMA_BF16(A0##SUF, B1##SUF, acc[0][1], 0, 0, 0); \
        acc[1][1] = MFMA_BF16(fA1, B1##SUF, acc[1][1], 0, 0, 0); \
        acc[2][1] = MFMA_BF16(fA2, B1##SUF, acc[2][1], 0, 0, 0); \
        acc[0][2] = MFMA_BF16(A0##SUF, B2##SUF, acc[0][2], 0, 0, 0); \
        acc[1][2] = MFMA_BF16(fA1, B2##SUF, acc[1][2], 0, 0, 0); \
        acc[2][2] = MFMA_BF16(fA2, B2##SUF, acc[2][2], 0, 0, 0); \
        acc[0][3] = MFMA_BF16(A0##SUF, B3##SUF, acc[0][3], 0, 0, 0); \
        acc[1][3] = MFMA_BF16(fA1, B3##SUF, acc[1][3], 0, 0, 0); \
        acc[2][3] = MFMA_BF16(fA2, B3##SUF, acc[2][3], 0, 0, 0); } while (0)
        // drain unrelated VMEM so manual vmcnt counting is exact
        WAITN(0);
        LDG5(a, 0); LDG5(b, 64); LDG5(c, 128);
        LDA(0);  WAITN(10); CPSTEP(a); LDG5(a, 192);
        LDA(1);  WAITN(10); CPSTEP(b); LDG5(b, 256);
        LDA(2);  WAITN(10); CPSTEP(c); LDG5(c, 320);
        LDA(3);  WAITN(10); CPSTEP(a); LDG5(a, 384);
        LDA(4);  WAITN(10); CPSTEP(b); LDG5(b, 448);
        LDA(5);  WAITN(10); CPSTEP(c); LDG5(c, 512);
        LDA(6);  WAITN(10); CPSTEP(a); LDG5(a, 576);
        LDA(7);  WAITN(10); CPSTEP(b); LDG5(b, 640);
        LDA(8);  WAITN(10); CPSTEP(c); LDG5(c, 704);
        LDA(9);  WAITN(10); CPSTEP(a); LDG5(a, 768);
        LDA(10); WAITN(10); CPSTEP(b); LDG5(b, 832);
        LDA(11); WAITN(10); CPSTEP(c); LDG5(c, 896);
        LDA(12); WAITN(10); CPSTEP(a); LDG5(a, 960);
        LDA(13); WAITN(10); CPSTEP(b); LDG5(b, 1024);
        LDA(14); WAITN(10); CPSTEP(c); LDG5(c, 1088);
        LDA(15); WAITN(10); CPSTEP(a); LDG5(a, 1152);
        LDA(16); WAITN(10); CPSTEP(b); LDG5(b, 1216);
        LDA(17); WAITN(10); CPSTEP(c); LDG5(c, 1280);
        LDA(18); WAITN(10); CPSTEP(a); LDG5(a, 1344);
        LDA(19); WAITN(10); CPSTEP(b); LDG5(b, 1408);
        LDA(20); WAITN(10); CPSTEP(c); LDG5(c, 1472);
        LDA(21); WAITN(10); CPSTEP(a);
        LDA(22); WAITN(5);  CPSTEP(b);
        LDA(23); WAITN(0);  CPSTEP(c);
#undef GL_
#undef GL
#undef LDG5
#undef LDA
#undef WAITN_
#undef WAITN
#undef CPSTEP
        // fold to masked bf16 scores
        #pragma unroll
        for (int cc = 0; cc < 4; ++cc) {
            int c = g * 4 + cc;
            if (c < nchunk) {
                int m = msta + c * 128 + wave * 16 + lrow;
                bool ok = (m > sep) && (ldid(ids, (size_t)b * L + m, is64) != pad);
                float vs[4], vc[4];
                #pragma unroll
                for (int r = 0; r < 4; ++r) {
                    vs[r] = ok ? acc[0][cc][r] * SCALE : NEGV;
                    vc[r] = ok ? (acc[2][cc][r] * SCALE
                                  + tanhf((acc[1][cc][r] + tcv[r]) * SCALE)) : NEGV;
                }
                pS[c][0] = (unsigned)f2b(vs[0]) | ((unsigned)f2b(vs[1]) << 16);
                pS[c][1] = (unsigned)f2b(vs[2]) | ((unsigned)f2b(vs[3]) << 16);
                pC[c][0] = (unsigned)f2b(vc[0]) | ((unsigned)f2b(vc[1]) << 16);
                pC[c][1] = (unsigned)f2b(vc[2]) | ((unsigned)f2b(vc[3]) << 16);
            }
        }
      }
    }
    // ---- row max (over lrow within wave, then across 8 waves) ----
    float mxs[4], mxc[4];
    #pragma unroll
    for (int r = 0; r < 4; ++r) { mxs[r] = -3.4e38f; mxc[r] = -3.4e38f; }
    #pragma unroll
    for (int c = 0; c < 8; ++c) if (c < nchunk)
        #pragma unroll
        for (int r = 0; r < 4; ++r) {
            mxs[r] = fmaxf(mxs[r], unpk(pS[c][r >> 1], r & 1));
            mxc[r] = fmaxf(mxc[r], unpk(pC[c][r >> 1], r & 1));
        }
    #pragma unroll
    for (int d = 1; d < 16; d <<= 1)
        #pragma unroll
        for (int r = 0; r < 4; ++r) {
            mxs[r] = fmaxf(mxs[r], __shfl_xor(mxs[r], d));
            mxc[r] = fmaxf(mxc[r], __shfl_xor(mxc[r], d));
        }
    if (lrow == 0)
        #pragma unroll
        for (int r = 0; r < 4; ++r) {
            redmx[0][wave][quad * 4 + r] = mxs[r];
            redmx[1][wave][quad * 4 + r] = mxc[r];
        }
    __syncthreads();
    #pragma unroll
    for (int r = 0; r < 4; ++r) {
        int rr = quad * 4 + r;
        float m0 = redmx[0][0][rr], m1 = redmx[1][0][rr];
        #pragma unroll
        for (int w = 1; w < 8; ++w) {
            m0 = fmaxf(m0, redmx[0][w][rr]);
            m1 = fmaxf(m1, redmx[1][w][rr]);
        }
        mxs[r] = m0; mxc[r] = m1;
    }
    // ---- row sum ----
    float sms[4], smc[4];
    #pragma unroll
    for (int r = 0; r < 4; ++r) { sms[r] = 0.f; smc[r] = 0.f; }
    #pragma unroll
    for (int c = 0; c < 8; ++c) if (c < nchunk)
        #pragma unroll
        for (int r = 0; r < 4; ++r) {
            sms[r] += expf(unpk(pS[c][r >> 1], r & 1) - mxs[r]);
            smc[r] += expf(unpk(pC[c][r >> 1], r & 1) - mxc[r]);
        }
    #pragma unroll
    for (int d = 1; d < 16; d <<= 1)
        #pragma unroll
        for (int r = 0; r < 4; ++r) {
            sms[r] += __shfl_xor(sms[r], d);
            smc[r] += __shfl_xor(smc[r], d);
        }
    if (lrow == 0)
        #pragma unroll
        for (int r = 0; r < 4; ++r) {
            redsm[0][wave][quad * 4 + r] = sms[r];
            redsm[1][wave][quad * 4 + r] = smc[r];
        }
    __syncthreads();
    float wgs[4], wgc[4];
    #pragma unroll
    for (int r = 0; r < 4; ++r) {
        int rr = quad * 4 + r;
        float d0 = redsm[0][0][rr], d1 = redsm[1][0][rr];
        #pragma unroll
        for (int w = 1; w < 8; ++w) {
            d0 += redsm[0][w][rr];
            d1 += redsm[1][w][rr];
        }
        wgs[r] = gr[r] / fmaxf(d0, 1e-30f);
        wgc[r] = gr[r] / fmaxf(d1, 1e-30f);
    }
    // ---- gated column accumulation ----
    #pragma unroll
    for (int c = 0; c < 8; ++c) if (c < nchunk) {
        float as = 0.f, ar = 0.f;
        #pragma unroll
        for (int r = 0; r < 4; ++r) {
            as += wgs[r] * expf(unpk(pS[c][r >> 1], r & 1) - mxs[r]);
            ar += wgc[r] * expf(unpk(pC[c][r >> 1], r & 1) - mxc[r]);
        }
        as += __shfl_xor(as, 16); as += __shfl_xor(as, 32);
        ar += __shfl_xor(ar, 16); ar += __shfl_xor(ar, 32);
        if (quad == 0) {
            int m = msta + c * 128 + wave * 16 + lrow;
            atomicAdd(&csup[b * L + m], as);
            atomicAdd(&crep[b * L + m], ar);
        }
    }
}

// ---------------- K3: af/w_rep/w_sup weighted sums over xb (bf16) ----------------
__global__ __launch_bounds__(256) void k3(const u16* __restrict__ xb,
        const float* __restrict__ gate, const float* __restrict__ csup,
        const float* __restrict__ crep, float* __restrict__ af,
        float* __restrict__ wrep, float* __restrict__ wsup) {
    int b = blockIdx.y, c = blockIdx.x;
    int tid = threadIdx.x;
    float a0 = 0.f, a1 = 0.f, a2 = 0.f;
    float r0 = 0.f, r1 = 0.f, r2 = 0.f;
    float q0 = 0.f, q1 = 0.f, q2 = 0.f;
    for (int mm = 0; mm < 16; ++mm) {
        int m = c * 16 + mm;
        float wg = gate[b * L + m], wr = crep[b * L + m], wq = csup[b * L + m];
        if (wg == 0.f && wr == 0.f && wq == 0.f) continue;
        size_t base = ((size_t)b * L + m) * D;
        float x0 = b2f(xb[base + tid]);
        float x1 = b2f(xb[base + tid + 256]);
        float x2 = b2f(xb[base + tid + 512]);
        a0 += wg * x0; a1 += wg * x1; a2 += wg * x2;
        r0 += wr * x0; r1 += wr * x1; r2 += wr * x2;
        q0 += wq * x0; q1 += wq * x1; q2 += wq * x2;
    }
    atomicAdd(&af[b * D + tid], a0); atomicAdd(&af[b * D + tid + 256], a1); atomicAdd(&af[b * D + tid + 512], a2);
    atomicAdd(&wrep[b * D + tid], r0); atomicAdd(&wrep[b * D + tid + 256], r1); atomicAdd(&wrep[b * D + tid + 512], r2);
    atomicAdd(&wsup[b * D + tid], q0); atomicAdd(&wsup[b * D + tid + 256], q1); atomicAdd(&wsup[b * D + tid + 512], q2);
}

// ---------------- kh1: hacc += fused @ Wf1 (split-K) ----------------
template<int F32> __device__ void kh1_body(const float* af, const float* wrep,
        const float* wsup, const void* Wf1, float* hacc, float* fs) {
    int tid = threadIdx.x;
    int c0 = blockIdx.x * 128, k0 = blockIdx.y * 144;
    for (int e = tid; e < 8 * 144; e += 256) {
        int b = e / 144, kk = e - b * 144;
        int k = k0 + kk;
        float v = (k < D) ? af[b * D + k] : (k < 2 * D) ? wrep[b * D + k - D]
                                                        : wsup[b * D + k - 2 * D];
        fs[b * 144 + kk] = v;
    }
    __syncthreads();
    int col = c0 + (tid & 127);
    int kg = tid >> 7;
    float acc[NB];
    #pragma unroll
    for (int b = 0; b < NB; ++b) acc[b] = 0.f;
    #pragma unroll 4
    for (int r = 0; r < 72; ++r) {
        int kk = kg * 72 + r;
        float w = ld1<F32>(Wf1, (size_t)(k0 + kk) * D + col);
        #pragma unroll
        for (int b = 0; b < NB; ++b) acc[b] += fs[b * 144 + kk] * w;
    }
    #pragma unroll
    for (int b = 0; b < NB; ++b) atomicAdd(&hacc[b * D + col], acc[b]);
}
__global__ __launch_bounds__(256) void kh1(const void* x, const int* ids,
        const float* af, const float* wrep,
        const float* wsup, const void* Wf1, float* hacc) {
    __shared__ float fs[8 * 144];
    __shared__ int fsh[2];
    detect2(x, ids, fsh);
    if (fsh[0]) kh1_body<1>(af, wrep, wsup, Wf1, hacc, fs);
    else        kh1_body<0>(af, wrep, wsup, Wf1, hacc, fs);
}

// ---------------- kh2: oacc += relu(hacc+bf1) @ Wf2 (split-K) ----------------
template<int F32> __device__ void kh2_body(const float* hacc, const void* bf1,
        const void* Wf2, float* oacc, float* hsl) {
    int tid = threadIdx.x;
    int c0 = blockIdx.x * 128, k0 = blockIdx.y * 96;
    for (int e = tid; e < 8 * 96; e += 256) {
        int b = e / 96, kk = e - b * 96;
        int k = k0 + kk;
        hsl[b * 96 + kk] = fmaxf(hacc[b * D + k] + ld1<F32>(bf1, k), 0.f);
    }
    __syncthreads();
    int col = c0 + (tid & 127);
    int kg = tid >> 7;
    float acc[NB];
    #pragma unroll
    for (int b = 0; b < NB; ++b) acc[b] = 0.f;
    #pragma unroll 4
    for (int r = 0; r < 48; ++r) {
        int kk = kg * 48 + r;
        float w = ld1<F32>(Wf2, (size_t)(k0 + kk) * D + col);
        #pragma unroll
        for (int b = 0; b < NB; ++b) acc[b] += hsl[b * 96 + kk] * w;
    }
    #pragma unroll
    for (int b = 0; b < NB; ++b) atomicAdd(&oacc[b * D + col], acc[b]);
}
__global__ __launch_bounds__(256) void kh2(const void* x, const int* ids,
        const float* hacc, const void* bf1,
        const void* Wf2, float* oacc) {
    __shared__ float hsl[8 * 96];
    __shared__ int fsh[2];
    detect2(x, ids, fsh);
    if (fsh[0]) kh2_body<1>(hacc, bf1, Wf2, oacc, hsl);
    else        kh2_body<0>(hacc, bf1, Wf2, oacc, hsl);
}

// ---------------- kln: out = LN(oacc + bf2) * gamma + beta ----------------
template<int F32> __device__ void kln_body(const float* oacc, const void* bf2,
        const void* gamma, const void* beta, void* out, float* red) {
    int b = blockIdx.x, tid = threadIdx.x;
    float o[3];
    #pragma unroll
    for (int u = 0; u < 3; ++u) {
        int i = tid + u * 256;
        o[u] = oacc[b * D + i] + ld1<F32>(bf2, i);
    }
    red[tid] = o[0] + o[1] + o[2]; __syncthreads();
    for (int s = 128; s > 0; s >>= 1) { if (tid < s) red[tid] += red[tid + s]; __syncthreads(); }
    float mu = red[0] / (float)D; __syncthreads();
    float vs = 0.f;
    #pragma unroll
    for (int u = 0; u < 3; ++u) vs += (o[u] - mu) * (o[u] - mu);
    red[tid] = vs; __syncthreads();
    for (int s = 128; s > 0; s >>= 1) { if (tid < s) red[tid] += red[tid + s]; __syncthreads(); }
    float var = red[0] / (float)D;
    float rstd = 1.0f / sqrtf(var + 1e-5f);
    #pragma unroll
    for (int u = 0; u < 3; ++u) {
        int i = tid + u * 256;
        float v = (o[u] - mu) * rstd * ld1<F32>(gamma, i) + ld1<F32>(beta, i);
        if (F32) ((float*)out)[b * D + i] = v;
        else     ((u16*)out)[b * D + i] = f2b(v);
    }
}
__global__ __launch_bounds__(256) void kln(const void* x, const int* ids,
        const float* oacc, const void* bf2,
        const void* gamma, const void* beta, void* out) {
    __shared__ float red[256];
    __shared__ int fsh[2];
    detect2(x, ids, fsh);
    if (fsh[0]) kln_body<1>(oacc, bf2, gamma, beta, out, red);
    else        kln_body<0>(oacc, bf2, gamma, beta, out, red);
}

extern "C" void kernel_launch(void* const* d_in, const int* in_sizes, int n_in,
                              void* d_out, int out_size, void* d_ws, size_t ws_size,
                              hipStream_t stream) {
    const void* x    = d_in[0];
    const int* ids   = (const int*)d_in[1];
    const int* padp  = (const int*)d_in[2];
    const void* Wa   = d_in[3];
    const void* ba   = d_in[4];
    PP pp;
    pp.W[0] = d_in[5];  pp.b[0] = d_in[6];    // qs
    pp.W[1] = d_in[7];  pp.b[1] = d_in[8];    // ks
    pp.W[2] = d_in[9];  pp.b[2] = d_in[10];   // qc
    pp.W[3] = d_in[11]; pp.b[3] = d_in[12];   // kc
    pp.W[4] = d_in[13]; pp.b[4] = d_in[14];   // qr
    pp.W[5] = d_in[15]; pp.b[5] = d_in[16];   // kr
    const void* Wf1 = d_in[17]; const void* bf1 = d_in[18];
    const void* Wf2 = d_in[19]; const void* bf2 = d_in[20];
    const void* gamma = d_in[21]; const void* beta = d_in[22];

    char* ws = (char*)d_ws;
    int*   sepArr = (int*)(ws + WS_SEP);
    float* c0   = (float*)(ws + WS_C0);
    float* z0   = (float*)(ws + WS_Z0);
    float* w1   = (float*)(ws + WS_W1);
    float* gate = (float*)(ws + WS_GATE);
    float* csup = (float*)(ws + WS_CSUP);
    float* crep = (float*)(ws + WS_CREP);
    float* af   = (float*)(ws + WS_AF);
    float* wrep = (float*)(ws + WS_WREP);
    float* wsup = (float*)(ws + WS_WSUP);
    float* hacc = (float*)(ws + WS_HACC);
    float* oacc = (float*)(ws + WS_OACC);
    float* alog = (float*)(ws + WS_ALOG);
    float* tbuf = (float*)(ws + WS_T);
    u16* xb   = (u16*)(ws + WS_XB);
    u16* Zbuf = (u16*)(ws + WS_Z);
    u16* Wb   = (u16*)(ws + WS_WB);
    u16* Mt   = (u16*)(ws + WS_M);

    kx<<<dim3(2044), dim3(256), 0, stream>>>(x, ids, pp, Wa, ba, xb, Wb, alog, z0, w1, c0);
    kB<<<dim3(256), dim3(256), 0, stream>>>(x, ids, padp, alog, gate, sepArr,
                                            af, wrep, wsup, hacc, oacc, csup, crep,
                                            xb, w1, c0, tbuf, Wb, Mt);
    kZ_mfma<<<dim3(6, 4, 24), dim3(256), 0, stream>>>(xb, Mt, z0, Zbuf, sepArr);
    kS2<<<dim3(256), dim3(512), 0, stream>>>(Zbuf, xb, tbuf, sepArr, ids, padp,
                                             gate, csup, crep);
    k3<<<dim3(64, NB), dim3(256), 0, stream>>>(xb, gate, csup, crep, af, wrep, wsup);
    kh1<<<dim3(6, 16), dim3(256), 0, stream>>>(x, ids, af, wrep, wsup, Wf1, hacc);
    kh2<<<dim3(6, 8), dim3(256), 0, stream>>>(x, ids, hacc, bf1, Wf2, oacc);
    kln<<<dim3(NB), dim3(256), 0, stream>>>(x, ids, oacc, bf2, gamma, beta, d_out);
}